// Round 2
// baseline (431.725 us; speedup 1.0000x reference)
//
#include <hip/hip_runtime.h>
#include <math.h>

// CovidModel: M[t][s] = sum_j A_full[J+t-1-j][s] * rho[s] * pi[j][s]
// A recursion in closed form:  A[d][s] = A0[s] * exp2(invT[s]*L[d] + (d+1)*log2(delta[s]))
// L[d] = prefix sum of log2(r_t) (sample-independent, in d_ws).
//
// Round-2 restructure: 2 samples per lane as float2 -> v_pk_fma_f32 (packed
// f32, full rate). Halves wave count and store-inst count at constant
// per-wave issue; doubles per-wave ILP. State (w2[32]+ring2[32] = 128 VGPR)
// -> ~3 waves/SIMD via __launch_bounds__(64,3). 64-thread 1-wave blocks +
// DT=64 keep packing granularity fine (6256 blocks, ~12 resident/CU).
// Round-1 falsified: L-access method (LDS vs scalar) and init amortization
// are NOT on the critical path -- both variants identical at ~122 us.

#define T_DAYS 1024
#define J_WIN  32
#define DT     64            // days per block; 2 groups of 32
#define GROUPS (DT / 32)

typedef float f32x2 __attribute__((ext_vector_type(2)));

// Kernel 1: L[t] = inclusive prefix sum of log2(r_t[t]); one block.
__global__ void prefix_log_kernel(const float* __restrict__ r_t,
                                  float* __restrict__ L) {
    __shared__ float buf[T_DAYS];
    const int i = threadIdx.x;
    buf[i] = __log2f(r_t[i]);
    __syncthreads();
    for (int off = 1; off < T_DAYS; off <<= 1) {
        float add = (i >= off) ? buf[i - off] : 0.0f;
        __syncthreads();
        buf[i] += add;
        __syncthreads();
    }
    L[i] = buf[i];
}

// Kernel 2: main forecast. TWO samples per lane (float2), DT days per block.
__global__ __launch_bounds__(64, 3)
void covid_kernel(const float* __restrict__ warmup_A,
                  const float* __restrict__ delta_p,
                  const float* __restrict__ T_serial,
                  const float* __restrict__ rho_p,
                  const float* __restrict__ pi_M,
                  const float* __restrict__ L,
                  float* __restrict__ out,
                  int S) {
    const int p = blockIdx.x * 64 + threadIdx.x;  // sample-pair index
    const int s = 2 * p;                          // S is even (50000)
    if (s >= S) return;
    const int t0 = blockIdx.y * DT;               // multiple of 64

    const f32x2 Ts  = *(const f32x2*)&T_serial[s];
    const f32x2 dlt = *(const f32x2*)&delta_p[s];
    const f32x2 rho = *(const f32x2*)&rho_p[s];
    const f32x2 A0  = *(const f32x2*)&warmup_A[(J_WIN - 1) * S + s];
    f32x2 invT, ld;
    invT.x = 1.0f / Ts.x;        invT.y = 1.0f / Ts.y;
    ld.x   = __log2f(dlt.x);     ld.y   = __log2f(dlt.y);

    // Folded weights w[j] = rho * pi[j][s..s+1] (registers, static-indexed)
    f32x2 w[J_WIN];
#pragma unroll
    for (int j = 0; j < J_WIN; ++j) {
        const f32x2 pi2 = *(const f32x2*)&pi_M[j * S + s];
        w[j].x = rho.x * pi2.x;
        w[j].y = rho.y * pi2.y;
    }

    // Ring: A(day d) at ring[d mod 32] (warmup day d<0 at d+32).
    // Group bases are multiples of 32, so init day t0-32+k sits at slot k.
    f32x2 ring[J_WIN];
    if (t0 == 0) {
#pragma unroll
        for (int k = 0; k < J_WIN; ++k)
            ring[k] = *(const f32x2*)&warmup_A[k * S + s];
    } else {
#pragma unroll
        for (int k = 0; k < J_WIN; ++k) {
            const float Lk = L[t0 - J_WIN + k];   // block-uniform -> s_load
            const float dn = (float)(t0 - J_WIN + k + 1);
            ring[k].x = A0.x * __builtin_amdgcn_exp2f(fmaf(invT.x, Lk, dn * ld.x));
            ring[k].y = A0.y * __builtin_amdgcn_exp2f(fmaf(invT.y, Lk, dn * ld.y));
        }
    }

    f32x2 c;                                      // (d+1)*ld for next A-day
    c.x = (float)(t0 + 1) * ld.x;
    c.y = (float)(t0 + 1) * ld.y;
    float* op = out + (size_t)t0 * S + s;
    int tg = t0;
#pragma unroll 1   // keep the 32-day body rolled once: code size stays small
    for (int g = 0; g < GROUPS; ++g) {
#pragma unroll
        for (int u = 0; u < 32; ++u) {
            // M[tg+u] = sum_j w[j] * A(tg+u-1-j); ring slot (u-1-j)&31 is a
            // compile-time constant after unrolling. 4 independent pk chains.
            f32x2 m0 = {0.0f, 0.0f}, m1 = {0.0f, 0.0f};
            f32x2 m2 = {0.0f, 0.0f}, m3 = {0.0f, 0.0f};
#pragma unroll
            for (int j = 0; j < J_WIN; j += 4) {
                m0 = __builtin_elementwise_fma(w[j + 0], ring[(u - 1 - j) & 31], m0);
                m1 = __builtin_elementwise_fma(w[j + 1], ring[(u - 2 - j) & 31], m1);
                m2 = __builtin_elementwise_fma(w[j + 2], ring[(u - 3 - j) & 31], m2);
                m3 = __builtin_elementwise_fma(w[j + 3], ring[(u - 4 - j) & 31], m3);
            }
            f32x2 m;
            m.x = (m0.x + m1.x) + (m2.x + m3.x);
            m.y = (m0.y + m1.y) + (m2.y + m3.y);
            *(f32x2*)(op + (size_t)u * S) = m;    // dwordx2 store, 512 B/wave
            // A(tg+u) closed form; overwrites oldest slot (day tg+u-32).
            const float Lu = L[tg + u];           // block-uniform -> s_load
            ring[u].x = A0.x * __builtin_amdgcn_exp2f(fmaf(invT.x, Lu, c.x));
            ring[u].y = A0.y * __builtin_amdgcn_exp2f(fmaf(invT.y, Lu, c.y));
            c.x += ld.x;
            c.y += ld.y;
        }
        op += (size_t)32 * S;
        tg += 32;
    }
}

extern "C" void kernel_launch(void* const* d_in, const int* in_sizes, int n_in,
                              void* d_out, int out_size, void* d_ws, size_t ws_size,
                              hipStream_t stream) {
    const float* r_t      = (const float*)d_in[0];
    const float* warmup_A = (const float*)d_in[1];
    const float* delta    = (const float*)d_in[2];
    const float* T_serial = (const float*)d_in[3];
    const float* rho_M    = (const float*)d_in[4];
    const float* pi_M     = (const float*)d_in[5];
    float* out = (float*)d_out;
    float* L   = (float*)d_ws;          // T_DAYS floats of scratch
    const int S = in_sizes[2];          // 50000

    prefix_log_kernel<<<1, T_DAYS, 0, stream>>>(r_t, L);

    const int pairs = (S + 1) / 2;
    dim3 grid((pairs + 63) / 64, T_DAYS / DT);
    covid_kernel<<<grid, 64, 0, stream>>>(warmup_A, delta, T_serial, rho_M,
                                          pi_M, L, out, S);
}

// Round 3
// 254.451 us; speedup vs baseline: 1.6967x; 1.6967x over previous
//
#include <hip/hip_runtime.h>
#include <math.h>

// CovidModel: M[t][s] = sum_j A_full[J+t-1-j][s] * rho[s] * pi[j][s]
// A recursion in closed form:  A[d][s] = A0[s]*exp2(invT[s]*L[d] + (d+1)*log2(delta[s]))
// L[d] = prefix sum of log2(r_t) (sample-independent, in d_ws).
//
// Round-3: keep 2-samples-per-lane (v_pk_fma_f32 path) but fix round-2's
// spill disaster:
//  - Round-2 evidence: VGPR_Count=84 with >=128 regs of live state => arrays
//    spilled to scratch; FETCH 338 MB / WRITE 628 MB (vs 13/205 ideal) was
//    spill traffic; kernel was HBM-bound on its own spills (989 MB @ 3.8 TB/s
//    = 259 us). Cause: 1-wave workgroup + __launch_bounds__(64,3) produced a
//    ~84-VGPR budget.
//  - Fix: 256-thread blocks (4-wave workgroups, sane allocation in r0/r1),
//    __launch_bounds__(256,2) -> 256-VGPR cap, ~160 needed -> no spill.
//  - Output stores nontemporal: write-once stream, keep L2 for pi/L.

#define T_DAYS 1024
#define J_WIN  32
#define DT     128           // days per block; 4 groups of 32
#define GROUPS (DT / 32)

typedef float f32x2 __attribute__((ext_vector_type(2)));

// Kernel 1: L[t] = inclusive prefix sum of log2(r_t[t]); one block.
__global__ void prefix_log_kernel(const float* __restrict__ r_t,
                                  float* __restrict__ L) {
    __shared__ float buf[T_DAYS];
    const int i = threadIdx.x;
    buf[i] = __log2f(r_t[i]);
    __syncthreads();
    for (int off = 1; off < T_DAYS; off <<= 1) {
        float add = (i >= off) ? buf[i - off] : 0.0f;
        __syncthreads();
        buf[i] += add;
        __syncthreads();
    }
    L[i] = buf[i];
}

// Kernel 2: main forecast. TWO samples per lane (float2), DT days per block.
__global__ __launch_bounds__(256, 2)
void covid_kernel(const float* __restrict__ warmup_A,
                  const float* __restrict__ delta_p,
                  const float* __restrict__ T_serial,
                  const float* __restrict__ rho_p,
                  const float* __restrict__ pi_M,
                  const float* __restrict__ L,
                  float* __restrict__ out,
                  int S) {
    const int p = blockIdx.x * 256 + threadIdx.x;  // sample-pair index
    const int s = 2 * p;                           // S is even (50000)
    if (s >= S) return;
    const int t0 = blockIdx.y * DT;                // multiple of 128

    const f32x2 Ts  = *(const f32x2*)&T_serial[s];
    const f32x2 dlt = *(const f32x2*)&delta_p[s];
    const f32x2 rho = *(const f32x2*)&rho_p[s];
    const f32x2 A0  = *(const f32x2*)&warmup_A[(J_WIN - 1) * S + s];
    f32x2 invT, ld;
    invT.x = 1.0f / Ts.x;        invT.y = 1.0f / Ts.y;
    ld.x   = __log2f(dlt.x);     ld.y   = __log2f(dlt.y);

    // Folded weights w[j] = rho * pi[j][s..s+1] (registers, static-indexed)
    f32x2 w[J_WIN];
#pragma unroll
    for (int j = 0; j < J_WIN; ++j) {
        const f32x2 pi2 = *(const f32x2*)&pi_M[j * S + s];
        w[j].x = rho.x * pi2.x;
        w[j].y = rho.y * pi2.y;
    }

    // Ring: A(day d) at ring[d mod 32] (warmup day d<0 at d+32).
    // Group bases are multiples of 32, so init day t0-32+k sits at slot k.
    f32x2 ring[J_WIN];
    if (t0 == 0) {
#pragma unroll
        for (int k = 0; k < J_WIN; ++k)
            ring[k] = *(const f32x2*)&warmup_A[k * S + s];
    } else {
#pragma unroll
        for (int k = 0; k < J_WIN; ++k) {
            const float Lk = L[t0 - J_WIN + k];    // block-uniform -> s_load
            const float dn = (float)(t0 - J_WIN + k + 1);
            ring[k].x = A0.x * __builtin_amdgcn_exp2f(fmaf(invT.x, Lk, dn * ld.x));
            ring[k].y = A0.y * __builtin_amdgcn_exp2f(fmaf(invT.y, Lk, dn * ld.y));
        }
    }

    f32x2 c;                                       // (d+1)*ld for next A-day
    c.x = (float)(t0 + 1) * ld.x;
    c.y = (float)(t0 + 1) * ld.y;
    float* op = out + (size_t)t0 * S + s;
    int tg = t0;
#pragma unroll 1   // keep the 32-day body rolled once: code size stays small
    for (int g = 0; g < GROUPS; ++g) {
#pragma unroll
        for (int u = 0; u < 32; ++u) {
            // M[tg+u] = sum_j w[j] * A(tg+u-1-j); ring slot (u-1-j)&31 is a
            // compile-time constant after unrolling. 4 independent pk chains.
            f32x2 m0 = {0.0f, 0.0f}, m1 = {0.0f, 0.0f};
            f32x2 m2 = {0.0f, 0.0f}, m3 = {0.0f, 0.0f};
#pragma unroll
            for (int j = 0; j < J_WIN; j += 4) {
                m0 = __builtin_elementwise_fma(w[j + 0], ring[(u - 1 - j) & 31], m0);
                m1 = __builtin_elementwise_fma(w[j + 1], ring[(u - 2 - j) & 31], m1);
                m2 = __builtin_elementwise_fma(w[j + 2], ring[(u - 3 - j) & 31], m2);
                m3 = __builtin_elementwise_fma(w[j + 3], ring[(u - 4 - j) & 31], m3);
            }
            f32x2 m;
            m.x = (m0.x + m1.x) + (m2.x + m3.x);
            m.y = (m0.y + m1.y) + (m2.y + m3.y);
            // write-once stream: nontemporal, keep L2 for pi/L
            __builtin_nontemporal_store(m, (f32x2*)(op + (size_t)u * S));
            // A(tg+u) closed form; overwrites oldest slot (day tg+u-32).
            const float Lu = L[tg + u];            // block-uniform -> s_load
            ring[u].x = A0.x * __builtin_amdgcn_exp2f(fmaf(invT.x, Lu, c.x));
            ring[u].y = A0.y * __builtin_amdgcn_exp2f(fmaf(invT.y, Lu, c.y));
            c.x += ld.x;
            c.y += ld.y;
        }
        op += (size_t)32 * S;
        tg += 32;
    }
}

extern "C" void kernel_launch(void* const* d_in, const int* in_sizes, int n_in,
                              void* d_out, int out_size, void* d_ws, size_t ws_size,
                              hipStream_t stream) {
    const float* r_t      = (const float*)d_in[0];
    const float* warmup_A = (const float*)d_in[1];
    const float* delta    = (const float*)d_in[2];
    const float* T_serial = (const float*)d_in[3];
    const float* rho_M    = (const float*)d_in[4];
    const float* pi_M     = (const float*)d_in[5];
    float* out = (float*)d_out;
    float* L   = (float*)d_ws;          // T_DAYS floats of scratch
    const int S = in_sizes[2];          // 50000

    prefix_log_kernel<<<1, T_DAYS, 0, stream>>>(r_t, L);

    const int pairs = (S + 1) / 2;
    dim3 grid((pairs + 255) / 256, T_DAYS / DT);
    covid_kernel<<<grid, 256, 0, stream>>>(warmup_A, delta, T_serial, rho_M,
                                           pi_M, L, out, S);
}

// Round 4
// 241.309 us; speedup vs baseline: 1.7891x; 1.0545x over previous
//
#include <hip/hip_runtime.h>
#include <math.h>

// CovidModel: M[t][s] = sum_j A_full[J+t-1-j][s] * rho[s] * pi[j][s]
// A in closed form: A[d][s] = A0[s]*exp2(invT[s]*L[d] + (d+1)*log2(delta[s]))
// L[d] = prefix sum of log2(r_t) (sample-independent, in d_ws).
//
// Round-4: the day loop is latency-bound, not issue-bound (evidence: scalar
// DT=32/LDS, scalar DT=128/sload, packed DT=128 all ~80 us vs ~15-32 us
// floors; halving VALU issue changed nothing). Remove per-day stalls:
//  - L values for a 32-day group hoisted to SGPRs (readfirstlane) at group
//    top -> one batched wait, no per-day s_load/wait in the unrolled body.
//  - Incremental store pointer (op += S): no per-day 64-bit address mul.
//  - A0 folded into w (ring carries A/A0): 2 fewer muls/day, shorter
//    exp2->store chain. t0==0 warmup ring scaled by 1/A0.
//  - Plain stores (NT hint showed no benefit in r3).

#define T_DAYS 1024
#define J_WIN  32
#define DT     128           // days per block; 4 groups of 32
#define GROUPS (DT / 32)

typedef float f32x2 __attribute__((ext_vector_type(2)));

// Kernel 1: L[t] = inclusive prefix sum of log2(r_t[t]); one block.
__global__ void prefix_log_kernel(const float* __restrict__ r_t,
                                  float* __restrict__ L) {
    __shared__ float buf[T_DAYS];
    const int i = threadIdx.x;
    buf[i] = __log2f(r_t[i]);
    __syncthreads();
    for (int off = 1; off < T_DAYS; off <<= 1) {
        float add = (i >= off) ? buf[i - off] : 0.0f;
        __syncthreads();
        buf[i] += add;
        __syncthreads();
    }
    L[i] = buf[i];
}

__device__ __forceinline__ float uload(const float* p) {
    // force block-uniform value into an SGPR
    return __uint_as_float(__builtin_amdgcn_readfirstlane(__float_as_uint(*p)));
}

// Kernel 2: main forecast. TWO samples per lane (float2), DT days per block.
__global__ __launch_bounds__(256, 2)
void covid_kernel(const float* __restrict__ warmup_A,
                  const float* __restrict__ delta_p,
                  const float* __restrict__ T_serial,
                  const float* __restrict__ rho_p,
                  const float* __restrict__ pi_M,
                  const float* __restrict__ L,
                  float* __restrict__ out,
                  int S) {
    const int p = blockIdx.x * 256 + threadIdx.x;  // sample-pair index
    const int s = 2 * p;                           // S is even (50000)
    if (s >= S) return;
    const int t0 = blockIdx.y * DT;                // multiple of 128

    const f32x2 Ts  = *(const f32x2*)&T_serial[s];
    const f32x2 dlt = *(const f32x2*)&delta_p[s];
    const f32x2 rho = *(const f32x2*)&rho_p[s];
    const f32x2 A0  = *(const f32x2*)&warmup_A[(J_WIN - 1) * S + s];
    f32x2 invT, ld;
    invT.x = 1.0f / Ts.x;        invT.y = 1.0f / Ts.y;
    ld.x   = __log2f(dlt.x);     ld.y   = __log2f(dlt.y);

    // w[j] = rho * A0 * pi[j]  (A0 folded in; ring carries A/A0)
    f32x2 rA0;
    rA0.x = rho.x * A0.x;  rA0.y = rho.y * A0.y;
    f32x2 w[J_WIN];
#pragma unroll
    for (int j = 0; j < J_WIN; ++j) {
        const f32x2 pi2 = *(const f32x2*)&pi_M[j * S + s];
        w[j].x = rA0.x * pi2.x;
        w[j].y = rA0.y * pi2.y;
    }

    // Ring carries A(day d)/A0 at ring[d mod 32] (warmup day d<0 at d+32).
    f32x2 ring[J_WIN];
    if (t0 == 0) {
        f32x2 iA0;
        iA0.x = 1.0f / A0.x;  iA0.y = 1.0f / A0.y;
#pragma unroll
        for (int k = 0; k < J_WIN; ++k) {
            const f32x2 wa = *(const f32x2*)&warmup_A[k * S + s];
            ring[k].x = wa.x * iA0.x;
            ring[k].y = wa.y * iA0.y;
        }
    } else {
#pragma unroll
        for (int k = 0; k < J_WIN; ++k) {
            const float Lk = uload(&L[t0 - J_WIN + k]);
            const float dn = (float)(t0 - J_WIN + k + 1);
            ring[k].x = __builtin_amdgcn_exp2f(fmaf(invT.x, Lk, dn * ld.x));
            ring[k].y = __builtin_amdgcn_exp2f(fmaf(invT.y, Lk, dn * ld.y));
        }
    }

    f32x2 c;                                       // (d+1)*ld for next A-day
    c.x = (float)(t0 + 1) * ld.x;
    c.y = (float)(t0 + 1) * ld.y;
    float* op = out + (size_t)t0 * S + s;
    int tg = t0;
#pragma unroll 1   // keep the 32-day body rolled once: code size stays small
    for (int g = 0; g < GROUPS; ++g) {
        // Hoist this group's 32 uniform L values into SGPRs: one batched
        // wait at group top instead of a per-day load+wait in the body.
        float Lg[32];
#pragma unroll
        for (int k = 0; k < 32; ++k) Lg[k] = uload(&L[tg + k]);
#pragma unroll
        for (int u = 0; u < 32; ++u) {
            // M[tg+u] = sum_j w[j] * A(tg+u-1-j); ring slot (u-1-j)&31 is a
            // compile-time constant after unrolling. 4 independent pk chains.
            f32x2 m0 = {0.0f, 0.0f}, m1 = {0.0f, 0.0f};
            f32x2 m2 = {0.0f, 0.0f}, m3 = {0.0f, 0.0f};
#pragma unroll
            for (int j = 0; j < J_WIN; j += 4) {
                m0 = __builtin_elementwise_fma(w[j + 0], ring[(u - 1 - j) & 31], m0);
                m1 = __builtin_elementwise_fma(w[j + 1], ring[(u - 2 - j) & 31], m1);
                m2 = __builtin_elementwise_fma(w[j + 2], ring[(u - 3 - j) & 31], m2);
                m3 = __builtin_elementwise_fma(w[j + 3], ring[(u - 4 - j) & 31], m3);
            }
            f32x2 m;
            m.x = (m0.x + m1.x) + (m2.x + m3.x);
            m.y = (m0.y + m1.y) + (m2.y + m3.y);
            *(f32x2*)op = m;
            op += S;                               // incremental row advance
            // A(tg+u)/A0 closed form; overwrites oldest slot (day tg+u-32).
            ring[u].x = __builtin_amdgcn_exp2f(fmaf(invT.x, Lg[u], c.x));
            ring[u].y = __builtin_amdgcn_exp2f(fmaf(invT.y, Lg[u], c.y));
            c.x += ld.x;
            c.y += ld.y;
        }
        tg += 32;
    }
}

extern "C" void kernel_launch(void* const* d_in, const int* in_sizes, int n_in,
                              void* d_out, int out_size, void* d_ws, size_t ws_size,
                              hipStream_t stream) {
    const float* r_t      = (const float*)d_in[0];
    const float* warmup_A = (const float*)d_in[1];
    const float* delta    = (const float*)d_in[2];
    const float* T_serial = (const float*)d_in[3];
    const float* rho_M    = (const float*)d_in[4];
    const float* pi_M     = (const float*)d_in[5];
    float* out = (float*)d_out;
    float* L   = (float*)d_ws;          // T_DAYS floats of scratch
    const int S = in_sizes[2];          // 50000

    prefix_log_kernel<<<1, T_DAYS, 0, stream>>>(r_t, L);

    const int pairs = (S + 1) / 2;
    dim3 grid((pairs + 255) / 256, T_DAYS / DT);
    covid_kernel<<<grid, 256, 0, stream>>>(warmup_A, delta, T_serial, rho_M,
                                           pi_M, L, out, S);
}

// Round 5
// 240.587 us; speedup vs baseline: 1.7945x; 1.0030x over previous
//
#include <hip/hip_runtime.h>
#include <math.h>

// CovidModel: M[t][s] = sum_j A_full[J+t-1-j][s] * rho[s] * pi[j][s]
// A in closed form: A[d][s] = A0[s]*exp2(invT[s]*L[d] + (d+1)*log2(delta[s]))
// L[d] = inclusive prefix sum of log2(r_t[d]) -- computed PER BLOCK in LDS
// (fused; the separate prefix kernel + its launch gap + global round-trip
// cost ~2 orders more than the ~1K-cycle per-block scan).
//
// Round-5 structural fixes (evidence: ~52 us residual constant across
// scalar/packed and 2-6 waves/SIMD => not latency, not issue):
//  - Grid granularity: 784 blocks = 256 CU x 3.06 -> makespan stretch
//    ceil(3.06)/3.06 = 1.31x. Now 128-thr blocks, DT=64 -> 3136 blocks =
//    256 x 12.25 -> stretch 1.06x, independent of occupancy.
//  - Dispatch count: prefix kernel fused away (one less launch gap).
//  - Keep: f32x2 packed (v_pk_fma_f32), w=rho*A0*pi folded, L hoisted to
//    SGPRs per 32-day group, incremental store pointer, plain stores.
//  - __launch_bounds__(128,2): cap 256 VGPR (r2 lesson: tight bounds make
//    the backend derive a spill-inducing budget; natural pressure ~150).

#define T_DAYS 1024
#define J_WIN  32
#define DT     64            // days per block; 2 groups of 32
#define GROUPS (DT / 32)
#define BLK    128           // threads per block
#define CHUNK  (T_DAYS / BLK)  // 8 r_t elements per thread in the scan

typedef float f32x2 __attribute__((ext_vector_type(2)));

__device__ __forceinline__ float sgpr_of(float x) {
    // force a (block-uniform) value into an SGPR
    return __uint_as_float(__builtin_amdgcn_readfirstlane(__float_as_uint(x)));
}

__global__ __launch_bounds__(BLK, 2)
void covid_kernel(const float* __restrict__ r_t,
                  const float* __restrict__ warmup_A,
                  const float* __restrict__ delta_p,
                  const float* __restrict__ T_serial,
                  const float* __restrict__ rho_p,
                  const float* __restrict__ pi_M,
                  float* __restrict__ out,
                  int S) {
    __shared__ float Lsh[T_DAYS];
    __shared__ float tot[BLK];
    const int tid = threadIdx.x;

    // ---- fused prefix scan: Lsh[t] = sum_{i<=t} log2(r_t[i]) ----
    // (a) per-thread inclusive scan of 8 contiguous elements
    float v[CHUNK];
    {
        const float* rp = r_t + tid * CHUNK;
        float run = 0.0f;
#pragma unroll
        for (int k = 0; k < CHUNK; ++k) { run += __log2f(rp[k]); v[k] = run; }
        tot[tid] = run;
    }
    __syncthreads();
    // (b) Hillis-Steele scan of the 128 chunk totals
    for (int off = 1; off < BLK; off <<= 1) {
        float add = (tid >= off) ? tot[tid - off] : 0.0f;
        __syncthreads();
        tot[tid] += add;
        __syncthreads();
    }
    // (c) add exclusive chunk base, publish to Lsh
    {
        const float base = (tid > 0) ? tot[tid - 1] : 0.0f;
#pragma unroll
        for (int k = 0; k < CHUNK; ++k) Lsh[tid * CHUNK + k] = base + v[k];
    }
    __syncthreads();
    // ---- end scan (no further barriers below; early-exit is safe) ----

    const int p = blockIdx.x * BLK + tid;          // sample-pair index
    const int s = 2 * p;                           // S is even (50000)
    if (s >= S) return;
    const int t0 = blockIdx.y * DT;                // multiple of 64

    const f32x2 Ts  = *(const f32x2*)&T_serial[s];
    const f32x2 dlt = *(const f32x2*)&delta_p[s];
    const f32x2 rho = *(const f32x2*)&rho_p[s];
    const f32x2 A0  = *(const f32x2*)&warmup_A[(J_WIN - 1) * S + s];
    f32x2 invT, ld;
    invT.x = 1.0f / Ts.x;        invT.y = 1.0f / Ts.y;
    ld.x   = __log2f(dlt.x);     ld.y   = __log2f(dlt.y);

    // w[j] = rho * A0 * pi[j]  (A0 folded in; ring carries A/A0)
    f32x2 rA0;
    rA0.x = rho.x * A0.x;  rA0.y = rho.y * A0.y;
    f32x2 w[J_WIN];
#pragma unroll
    for (int j = 0; j < J_WIN; ++j) {
        const f32x2 pi2 = *(const f32x2*)&pi_M[j * S + s];
        w[j].x = rA0.x * pi2.x;
        w[j].y = rA0.y * pi2.y;
    }

    // Ring carries A(day d)/A0 at ring[d mod 32] (warmup day d<0 at d+32).
    f32x2 ring[J_WIN];
    if (t0 == 0) {
        f32x2 iA0;
        iA0.x = 1.0f / A0.x;  iA0.y = 1.0f / A0.y;
#pragma unroll
        for (int k = 0; k < J_WIN; ++k) {
            const f32x2 wa = *(const f32x2*)&warmup_A[k * S + s];
            ring[k].x = wa.x * iA0.x;
            ring[k].y = wa.y * iA0.y;
        }
    } else {
#pragma unroll
        for (int k = 0; k < J_WIN; ++k) {
            const float Lk = sgpr_of(Lsh[t0 - J_WIN + k]);
            const float dn = (float)(t0 - J_WIN + k + 1);
            ring[k].x = __builtin_amdgcn_exp2f(fmaf(invT.x, Lk, dn * ld.x));
            ring[k].y = __builtin_amdgcn_exp2f(fmaf(invT.y, Lk, dn * ld.y));
        }
    }

    f32x2 c;                                       // (d+1)*ld for next A-day
    c.x = (float)(t0 + 1) * ld.x;
    c.y = (float)(t0 + 1) * ld.y;
    float* op = out + (size_t)t0 * S + s;
    int tg = t0;
#pragma unroll 1   // keep the 32-day body rolled once: code size stays small
    for (int g = 0; g < GROUPS; ++g) {
        // Hoist this group's 32 uniform L values into SGPRs (one batched
        // LDS wait at group top, zero loads inside the unrolled body).
        float Lg[32];
#pragma unroll
        for (int k = 0; k < 32; ++k) Lg[k] = sgpr_of(Lsh[tg + k]);
#pragma unroll
        for (int u = 0; u < 32; ++u) {
            // M[tg+u] = sum_j w[j] * A(tg+u-1-j); ring slot (u-1-j)&31 is a
            // compile-time constant after unrolling. 4 independent pk chains.
            f32x2 m0 = {0.0f, 0.0f}, m1 = {0.0f, 0.0f};
            f32x2 m2 = {0.0f, 0.0f}, m3 = {0.0f, 0.0f};
#pragma unroll
            for (int j = 0; j < J_WIN; j += 4) {
                m0 = __builtin_elementwise_fma(w[j + 0], ring[(u - 1 - j) & 31], m0);
                m1 = __builtin_elementwise_fma(w[j + 1], ring[(u - 2 - j) & 31], m1);
                m2 = __builtin_elementwise_fma(w[j + 2], ring[(u - 3 - j) & 31], m2);
                m3 = __builtin_elementwise_fma(w[j + 3], ring[(u - 4 - j) & 31], m3);
            }
            f32x2 m;
            m.x = (m0.x + m1.x) + (m2.x + m3.x);
            m.y = (m0.y + m1.y) + (m2.y + m3.y);
            *(f32x2*)op = m;
            op += S;                               // incremental row advance
            // A(tg+u)/A0 closed form; overwrites oldest slot (day tg+u-32).
            ring[u].x = __builtin_amdgcn_exp2f(fmaf(invT.x, Lg[u], c.x));
            ring[u].y = __builtin_amdgcn_exp2f(fmaf(invT.y, Lg[u], c.y));
            c.x += ld.x;
            c.y += ld.y;
        }
        tg += 32;
    }
}

extern "C" void kernel_launch(void* const* d_in, const int* in_sizes, int n_in,
                              void* d_out, int out_size, void* d_ws, size_t ws_size,
                              hipStream_t stream) {
    const float* r_t      = (const float*)d_in[0];
    const float* warmup_A = (const float*)d_in[1];
    const float* delta    = (const float*)d_in[2];
    const float* T_serial = (const float*)d_in[3];
    const float* rho_M    = (const float*)d_in[4];
    const float* pi_M     = (const float*)d_in[5];
    float* out = (float*)d_out;
    const int S = in_sizes[2];          // 50000

    const int pairs = (S + 1) / 2;
    dim3 grid((pairs + BLK - 1) / BLK, T_DAYS / DT);
    covid_kernel<<<grid, BLK, 0, stream>>>(r_t, warmup_A, delta, T_serial,
                                           rho_M, pi_M, out, S);
}

// Round 6
// 233.228 us; speedup vs baseline: 1.8511x; 1.0316x over previous
//
#include <hip/hip_runtime.h>
#include <math.h>

// CovidModel: M[t][s] = sum_j A_full[J+t-1-j][s] * rho[s] * pi[j][s]
// A in closed form: A[d][s] = A0[s]*exp2(invT[s]*L[d] + (d+1)*log2(delta[s]))
// L[d] = inclusive prefix sum of log2(r_t[d]), computed per block in LDS.
//
// Round-6: consolidation of the only surviving levers (per-block
// amortization). Evidence ledger:
//  - r4 latency bundle (SGPR-L, incremental ptr, folded A0): -13 us. KEPT.
//  - r5: granularity (1.31x->1.06x stretch) and dispatch-fusion gains
//    cancelled exactly against 4x block-count preamble + 2x pi_M L3
//    refetch => per-block fixed cost ~1-1.5 us, pi refetch ~10 us scale.
//  - So: DT=256, BLK=128 -> grid (196,4)=784 blocks (r4's proven count,
//    half its y-rows): pi refetch 51->25.6 MB, preamble paid 784x not 3136x.
//  - Param/pi loads issued BEFORE the scan: the scan's first barrier drains
//    vmcnt anyway, so HBM/L3 latency hides under scan compute.
// Falsified (do not retry): issue-count halving, grid granularity,
// dispatch-count, NT stores, tight launch_bounds on 64-thr blocks (spills).

#define T_DAYS 1024
#define J_WIN  32
#define DT     256             // days per block; 8 groups of 32
#define GROUPS (DT / 32)
#define BLK    128             // threads per block
#define CHUNK  (T_DAYS / BLK)  // 8 r_t elements per thread in the scan

typedef float f32x2 __attribute__((ext_vector_type(2)));

__device__ __forceinline__ float sgpr_of(float x) {
    // force a (block-uniform) value into an SGPR
    return __uint_as_float(__builtin_amdgcn_readfirstlane(__float_as_uint(x)));
}

__global__ __launch_bounds__(BLK, 2)
void covid_kernel(const float* __restrict__ r_t,
                  const float* __restrict__ warmup_A,
                  const float* __restrict__ delta_p,
                  const float* __restrict__ T_serial,
                  const float* __restrict__ rho_p,
                  const float* __restrict__ pi_M,
                  float* __restrict__ out,
                  int S) {
    __shared__ float Lsh[T_DAYS];
    __shared__ float tot[BLK];
    const int tid = threadIdx.x;
    const int p = blockIdx.x * BLK + tid;          // sample-pair index
    const int s = 2 * p;                           // S is even (50000)
    const bool live = (s < S);
    const int sc = live ? s : 0;                   // clamped for safe loads

    // ---- issue per-sample loads EARLY: latency hides under the scan ----
    const f32x2 Ts  = *(const f32x2*)&T_serial[sc];
    const f32x2 dlt = *(const f32x2*)&delta_p[sc];
    const f32x2 rho = *(const f32x2*)&rho_p[sc];
    const f32x2 A0  = *(const f32x2*)&warmup_A[(J_WIN - 1) * S + sc];
    f32x2 pi2[J_WIN];
#pragma unroll
    for (int j = 0; j < J_WIN; ++j)
        pi2[j] = *(const f32x2*)&pi_M[j * S + sc];

    // ---- fused prefix scan: Lsh[t] = sum_{i<=t} log2(r_t[i]) ----
    float v[CHUNK];
    {
        const float* rp = r_t + tid * CHUNK;
        float run = 0.0f;
#pragma unroll
        for (int k = 0; k < CHUNK; ++k) { run += __log2f(rp[k]); v[k] = run; }
        tot[tid] = run;
    }
    __syncthreads();
    for (int off = 1; off < BLK; off <<= 1) {       // Hillis-Steele, 7 rounds
        float add = (tid >= off) ? tot[tid - off] : 0.0f;
        __syncthreads();
        tot[tid] += add;
        __syncthreads();
    }
    {
        const float base = (tid > 0) ? tot[tid - 1] : 0.0f;
#pragma unroll
        for (int k = 0; k < CHUNK; ++k) Lsh[tid * CHUNK + k] = base + v[k];
    }
    __syncthreads();
    // ---- end scan (no further barriers; early-exit safe) ----

    if (!live) return;
    const int t0 = blockIdx.y * DT;                 // multiple of 256

    f32x2 invT, ld;
    invT.x = 1.0f / Ts.x;        invT.y = 1.0f / Ts.y;
    ld.x   = __log2f(dlt.x);     ld.y   = __log2f(dlt.y);

    // w[j] = rho * A0 * pi[j]  (A0 folded in; ring carries A/A0)
    f32x2 rA0;
    rA0.x = rho.x * A0.x;  rA0.y = rho.y * A0.y;
    f32x2 w[J_WIN];
#pragma unroll
    for (int j = 0; j < J_WIN; ++j) {
        w[j].x = rA0.x * pi2[j].x;
        w[j].y = rA0.y * pi2[j].y;
    }

    // Ring carries A(day d)/A0 at ring[d mod 32] (warmup day d<0 at d+32).
    f32x2 ring[J_WIN];
    if (t0 == 0) {
        f32x2 iA0;
        iA0.x = 1.0f / A0.x;  iA0.y = 1.0f / A0.y;
#pragma unroll
        for (int k = 0; k < J_WIN; ++k) {
            const f32x2 wa = *(const f32x2*)&warmup_A[k * S + s];
            ring[k].x = wa.x * iA0.x;
            ring[k].y = wa.y * iA0.y;
        }
    } else {
#pragma unroll
        for (int k = 0; k < J_WIN; ++k) {
            const float Lk = sgpr_of(Lsh[t0 - J_WIN + k]);
            const float dn = (float)(t0 - J_WIN + k + 1);
            ring[k].x = __builtin_amdgcn_exp2f(fmaf(invT.x, Lk, dn * ld.x));
            ring[k].y = __builtin_amdgcn_exp2f(fmaf(invT.y, Lk, dn * ld.y));
        }
    }

    f32x2 c;                                        // (d+1)*ld for next A-day
    c.x = (float)(t0 + 1) * ld.x;
    c.y = (float)(t0 + 1) * ld.y;
    float* op = out + (size_t)t0 * S + s;
    int tg = t0;
#pragma unroll 1   // keep the 32-day body rolled once: code size stays small
    for (int g = 0; g < GROUPS; ++g) {
        // Hoist this group's 32 uniform L values into SGPRs (one batched
        // LDS wait at group top, zero loads inside the unrolled body).
        float Lg[32];
#pragma unroll
        for (int k = 0; k < 32; ++k) Lg[k] = sgpr_of(Lsh[tg + k]);
#pragma unroll
        for (int u = 0; u < 32; ++u) {
            // M[tg+u] = sum_j w[j] * A(tg+u-1-j); ring slot (u-1-j)&31 is a
            // compile-time constant after unrolling. 4 independent pk chains.
            f32x2 m0 = {0.0f, 0.0f}, m1 = {0.0f, 0.0f};
            f32x2 m2 = {0.0f, 0.0f}, m3 = {0.0f, 0.0f};
#pragma unroll
            for (int j = 0; j < J_WIN; j += 4) {
                m0 = __builtin_elementwise_fma(w[j + 0], ring[(u - 1 - j) & 31], m0);
                m1 = __builtin_elementwise_fma(w[j + 1], ring[(u - 2 - j) & 31], m1);
                m2 = __builtin_elementwise_fma(w[j + 2], ring[(u - 3 - j) & 31], m2);
                m3 = __builtin_elementwise_fma(w[j + 3], ring[(u - 4 - j) & 31], m3);
            }
            f32x2 m;
            m.x = (m0.x + m1.x) + (m2.x + m3.x);
            m.y = (m0.y + m1.y) + (m2.y + m3.y);
            *(f32x2*)op = m;
            op += S;                                // incremental row advance
            // A(tg+u)/A0 closed form; overwrites oldest slot (day tg+u-32).
            ring[u].x = __builtin_amdgcn_exp2f(fmaf(invT.x, Lg[u], c.x));
            ring[u].y = __builtin_amdgcn_exp2f(fmaf(invT.y, Lg[u], c.y));
            c.x += ld.x;
            c.y += ld.y;
        }
        tg += 32;
    }
}

extern "C" void kernel_launch(void* const* d_in, const int* in_sizes, int n_in,
                              void* d_out, int out_size, void* d_ws, size_t ws_size,
                              hipStream_t stream) {
    const float* r_t      = (const float*)d_in[0];
    const float* warmup_A = (const float*)d_in[1];
    const float* delta    = (const float*)d_in[2];
    const float* T_serial = (const float*)d_in[3];
    const float* rho_M    = (const float*)d_in[4];
    const float* pi_M     = (const float*)d_in[5];
    float* out = (float*)d_out;
    const int S = in_sizes[2];          // 50000

    const int pairs = (S + 1) / 2;
    dim3 grid((pairs + BLK - 1) / BLK, T_DAYS / DT);
    covid_kernel<<<grid, BLK, 0, stream>>>(r_t, warmup_A, delta, T_serial,
                                           rho_M, pi_M, out, S);
}